// Round 6
// baseline (873.886 us; speedup 1.0000x reference)
//
#include <hip/hip_runtime.h>
#include <math.h>

#define N_NODES 50000
#define N_PAD 50048          // multiple of 64 above 50000
#define N_EDGES 800000
#define DIM 256
#define N_GRAPHS 128
#define NSL 8                // dim slices (one per XCD)

using f32x4 = __attribute__((ext_vector_type(4))) float;
using s16x8 = __attribute__((ext_vector_type(8))) short;

// ---------------- bf16 helpers ----------------
__device__ __forceinline__ ushort bf16_hi(float f) {
  unsigned u = __float_as_uint(f);
  return (ushort)((u + 0x7FFFu + ((u >> 16) & 1u)) >> 16);
}
__device__ __forceinline__ float bf16_up(ushort h) {
  return __uint_as_float(((unsigned)h) << 16);
}
__device__ __forceinline__ void bf16_split(float f, ushort& hh, ushort& ll) {
  hh = bf16_hi(f);
  float d = f - bf16_up(hh);
  ll = bf16_hi(d);
}

// ---------------- CSR build (atomic count only) ----------------
__global__ __launch_bounds__(256) void count_kernel(
    const int* __restrict__ dst, int* __restrict__ counts,
    int* __restrict__ p_local) {
  int e = blockIdx.x * 256 + threadIdx.x;
  if (e < N_EDGES) p_local[e] = atomicAdd(&counts[dst[e]], 1);
}

#define SCAN_CHUNK 1024
#define SCAN_BLOCKS ((N_NODES + SCAN_CHUNK - 1) / SCAN_CHUNK)

__global__ __launch_bounds__(256) void scan_phaseA(
    const int* __restrict__ counts, int* __restrict__ blockSums) {
  __shared__ int sdata[256];
  int b = blockIdx.x, t = threadIdx.x;
  int base = b * SCAN_CHUNK + t * 4;
  int s = 0;
#pragma unroll
  for (int i = 0; i < 4; ++i) {
    int idx = base + i;
    if (idx < N_NODES) s += counts[idx];
  }
  sdata[t] = s;
  __syncthreads();
  for (int off = 128; off > 0; off >>= 1) {
    if (t < off) sdata[t] += sdata[t + off];
    __syncthreads();
  }
  if (t == 0) blockSums[b] = sdata[0];
}

__global__ void scan_phaseB(int* __restrict__ blockSums, int* __restrict__ rs) {
  if (threadIdx.x == 0 && blockIdx.x == 0) {
    int acc = 0;
    for (int i = 0; i < SCAN_BLOCKS; ++i) {
      int v = blockSums[i];
      blockSums[i] = acc;
      acc += v;
    }
    rs[N_NODES] = acc;
  }
}

__global__ __launch_bounds__(256) void scan_phaseC(
    const int* __restrict__ counts, const int* __restrict__ blockSums,
    int* __restrict__ rs) {
  __shared__ int sdata[256];
  int b = blockIdx.x, t = threadIdx.x;
  int base = b * SCAN_CHUNK + t * 4;
  int v[4];
  int s = 0;
#pragma unroll
  for (int i = 0; i < 4; ++i) {
    int idx = base + i;
    v[i] = (idx < N_NODES) ? counts[idx] : 0;
    s += v[i];
  }
  sdata[t] = s;
  __syncthreads();
  for (int off = 1; off < 256; off <<= 1) {
    int x = (t >= off) ? sdata[t - off] : 0;
    __syncthreads();
    sdata[t] += x;
    __syncthreads();
  }
  int excl = (t == 0) ? 0 : sdata[t - 1];
  int o = blockSums[b] + excl;
#pragma unroll
  for (int i = 0; i < 4; ++i) {
    int idx = base + i;
    if (idx < N_NODES) rs[idx] = o;
    o += v[i];
  }
}

// non-atomic fill: pos = rs[dst] + p_local
__global__ __launch_bounds__(256) void fill_kernel(
    const int* __restrict__ src, const int* __restrict__ dst,
    const float* __restrict__ ew, const int* __restrict__ rs,
    const int* __restrict__ p_local,
    int* __restrict__ csrc, float* __restrict__ cw) {
  int e = blockIdx.x * 256 + threadIdx.x;
  if (e < N_EDGES) {
    int d = dst[e];
    int pos = rs[d] + p_local[e];
    csrc[pos] = src[e];
    cw[pos] = ew[e];           // raw ew; normalized later
  }
}

// deg from CSR (coalesced, no atomics) + fused dinv
__global__ __launch_bounds__(256) void degsum_kernel(
    const int* __restrict__ rs, const float* __restrict__ cw,
    float* __restrict__ dinv) {
  int n = blockIdx.x * 256 + threadIdx.x;
  if (n >= N_NODES) return;
  int b = rs[n], e = rs[n + 1];
  float s = 1.0f;              // self-loop weight
  for (int i = b; i < e; ++i) s += cw[i];
  dinv[n] = 1.0f / sqrtf(s);
}

// cw[i] = dinv[src]*ew  (dst factor applied in spmm epilogue)
__global__ __launch_bounds__(256) void norm_kernel(
    const int* __restrict__ csrc, const float* __restrict__ dinv,
    float* __restrict__ cw) {
  int e = blockIdx.x * 256 + threadIdx.x;
  if (e < N_EDGES) cw[e] = cw[e] * dinv[csrc[e]];
}

// ---------------- input prep ----------------
// round emb_x to bf16, slice-major layout [NSL][N_PAD][32]
__global__ __launch_bounds__(256) void round_x_kernel(
    const float* __restrict__ x, ushort* __restrict__ tab, int n4) {
  int i = blockIdx.x * 256 + threadIdx.x;
  if (i >= n4) return;
  int n = i >> 6;              // node (DIM/4 = 64 quads per node)
  int q = i & 63;              // quad within row
  int s = q >> 3;              // slice (8 quads per slice)
  int c = (q & 7) * 4;         // dim within slice
  float4 v = ((const float4*)x)[i];
  ushort4 h;
  h.x = bf16_hi(v.x);
  h.y = bf16_hi(v.y);
  h.z = bf16_hi(v.z);
  h.w = bf16_hi(v.w);
  *(ushort4*)(tab + ((size_t)s * N_PAD + n) * 32 + c) = h;
}

// zero pad rows [N_NODES, N_PAD) of a slice-major table
__global__ __launch_bounds__(256) void pad0_kernel(ushort* __restrict__ tab) {
  int i = blockIdx.x * 256 + threadIdx.x;           // NSL*(N_PAD-N_NODES)*32
  int c = i & 31;
  int r = (i >> 5) % (N_PAD - N_NODES);
  int s = i / ((N_PAD - N_NODES) * 32);
  if (s < NSL) tab[((size_t)s * N_PAD + N_NODES + r) * 32 + c] = 0;
}

// transpose + split weights: W [K=256][N=256] f32 -> Wt_hi/Wt_lo [N][K] bf16
__global__ __launch_bounds__(256) void prep_w_kernel(
    const float* __restrict__ W1, const float* __restrict__ W2, const float* __restrict__ W3,
    ushort* __restrict__ wt) {
  int k = blockIdx.x;
  int w = blockIdx.y;
  int n = threadIdx.x;
  const float* W = (w == 0) ? W1 : (w == 1) ? W2 : W3;
  float v = W[k * 256 + n];
  ushort h, l;
  bf16_split(v, h, l);
  ushort* hplane = wt + (size_t)w * 2 * 256 * 256;
  ushort* lplane = hplane + 256 * 256;
  hplane[n * 256 + k] = h;
  lplane[n * 256 + k] = l;
}

// ---------------- bf16 MFMA GEMM (A + C slice-major, W hi+lo) ----------
// XW = round_bf16( A @ (Wh+Wl) ); BM=64, BN=256, BK=32, 4 waves.
#define GBM 64
#define GBK 32

__device__ __forceinline__ void gload16(const void* g, void* l) {
  __builtin_amdgcn_global_load_lds(
      (const __attribute__((address_space(1))) void*)g,
      (__attribute__((address_space(3))) void*)l, 16, 0, 0);
}

__global__ __launch_bounds__(256) void gemm_mfma(
    const ushort* __restrict__ A,                                  // [NSL][N_PAD][32]
    const ushort* __restrict__ Wh, const ushort* __restrict__ Wl,  // [256][256] n-major
    ushort* __restrict__ C, int M) {                               // [NSL][N_PAD][32]
  __shared__ ushort Asl[2][GBM * GBK];   // 2 x 4KB
  __shared__ ushort Bhs[2][256 * GBK];   // 2 x 16KB
  __shared__ ushort Bls[2][256 * GBK];   // 2 x 16KB
  int tid = threadIdx.x;
  int bm = blockIdx.x * GBM;
  int wave = tid >> 6, lane = tid & 63;
  int wc = wave * 64;
  int l15 = lane & 15;
  int lkb = lane >> 4;

  f32x4 acc[4][4];
#pragma unroll
  for (int i = 0; i < 4; ++i)
#pragma unroll
    for (int j = 0; j < 4; ++j) acc[i][j] = (f32x4){0.f, 0.f, 0.f, 0.f};

  int arow = tid & 63, akb = tid >> 6;   // A slot = tid = akb*64+arow

#define STAGE(buf, ts)                                                         \
  do {                                                                         \
    gload16(A + ((size_t)(ts) * N_PAD + bm + arow) * 32 + akb * 8,             \
            &Asl[buf][tid * 8]);                                               \
    _Pragma("unroll") for (int it = 0; it < 4; ++it) {                         \
      gload16(Wh + (size_t)tid * 256 + (ts) * 32 + it * 8,                     \
              &Bhs[buf][(it * 256 + tid) * 8]);                                \
      gload16(Wl + (size_t)tid * 256 + (ts) * 32 + it * 8,                     \
              &Bls[buf][(it * 256 + tid) * 8]);                                \
    }                                                                          \
  } while (0)

  STAGE(0, 0);
  __syncthreads();
  int cur = 0;
  for (int t = 0; t < 8; ++t) {
    if (t < 7) STAGE(cur ^ 1, t + 1);   // prefetch next k-step (= next slice)
    s16x8 af[4], bh[4], bl[4];
#pragma unroll
    for (int f = 0; f < 4; ++f) {
      af[f] = *(const s16x8*)(&Asl[cur][(lkb * 64 + f * 16 + l15) * 8]);
      bh[f] = *(const s16x8*)(&Bhs[cur][(lkb * 256 + wc + f * 16 + l15) * 8]);
      bl[f] = *(const s16x8*)(&Bls[cur][(lkb * 256 + wc + f * 16 + l15) * 8]);
    }
#pragma unroll
    for (int i = 0; i < 4; ++i)
#pragma unroll
      for (int j = 0; j < 4; ++j) {
        acc[i][j] = __builtin_amdgcn_mfma_f32_16x16x32_bf16(af[i], bh[j], acc[i][j], 0, 0, 0);
        acc[i][j] = __builtin_amdgcn_mfma_f32_16x16x32_bf16(af[i], bl[j], acc[i][j], 0, 0, 0);
      }
    __syncthreads();
    cur ^= 1;
  }
#undef STAGE

#pragma unroll
  for (int i = 0; i < 4; ++i) {
    int rbase = bm + i * 16 + (lane >> 4) * 4;
#pragma unroll
    for (int j = 0; j < 4; ++j) {
      int col = wc + j * 16 + l15;
      size_t cbase = (size_t)(col >> 5) * N_PAD * 32 + (col & 31);
#pragma unroll
      for (int r = 0; r < 4; ++r) {
        int row = rbase + r;
        if (row < M) C[cbase + (size_t)row * 32] = bf16_hi(acc[i][j][r]);
      }
    }
  }
}

// ---------------- XCD-sliced SpMM ----------------
// block = 4 waves = 4 nodes, slice = blockIdx&7 (~XCD id via round-robin).
// Per wave: eg = lane>>4 handles every-4th edge; dp = lane&15 owns 2 dims.
// result = di * sum(cw_norm * x_src) + di^2 * x_self + bias, relu.
// MODE 0: write bf16 slice-major table; MODE 1: write f32 row-major.
template <int MODE>
__global__ __launch_bounds__(256) void spmm_slice(
    const ushort* __restrict__ tab, const int* __restrict__ rs,
    const int* __restrict__ csrc, const float* __restrict__ cw,
    const float* __restrict__ dinv, const float* __restrict__ bias,
    float* __restrict__ xf32, ushort* __restrict__ xout) {
  int bid = blockIdx.x;
  int s = bid & 7;
  int g = bid >> 3;
  int wave = threadIdx.x >> 6, lane = threadIdx.x & 63;
  int n = g * 4 + wave;              // 50000 = 12500*4
  int eg = lane >> 4, dp = lane & 15;
  float di = dinv[n];
  const ushort* srow = tab + ((size_t)s * N_PAD + n) * 32 + dp * 2;
  unsigned selfu = *(const unsigned*)srow;
  float sx = bf16_up((ushort)(selfu & 0xffff));
  float sy = bf16_up((ushort)(selfu >> 16));
  float ax = 0.f, ay = 0.f;
  int beg = rs[n], end = rs[n + 1];
  for (int i = beg + eg; i < end; i += 4) {
    int idx = csrc[i];
    float w = cw[i];
    unsigned v = *(const unsigned*)(tab + ((size_t)s * N_PAD + idx) * 32 + dp * 2);
    ax += w * bf16_up((ushort)(v & 0xffff));
    ay += w * bf16_up((ushort)(v >> 16));
  }
  ax += __shfl_xor(ax, 16);
  ay += __shfl_xor(ay, 16);
  ax += __shfl_xor(ax, 32);
  ay += __shfl_xor(ay, 32);
  if (eg == 0) {
    float dd = di * di;
    int d = s * 32 + dp * 2;
    float rx = fmaxf(di * ax + dd * sx + bias[d], 0.f);
    float ry = fmaxf(di * ay + dd * sy + bias[d + 1], 0.f);
    if (MODE == 1) {
      float2 r2;
      r2.x = rx;
      r2.y = ry;
      *(float2*)(xf32 + (size_t)n * 256 + d) = r2;
    } else {
      unsigned hv = (unsigned)bf16_hi(rx) | ((unsigned)bf16_hi(ry) << 16);
      *(unsigned*)(xout + ((size_t)s * N_PAD + n) * 32 + dp * 2) = hv;
    }
  }
}

// ---------------- pooling ----------------
__device__ __forceinline__ int lower_bound_dev(const int* a, int n, int key) {
  int lo = 0, hi = n;
  while (lo < hi) {
    int mid = (lo + hi) >> 1;
    if (a[mid] < key) lo = mid + 1; else hi = mid;
  }
  return lo;
}

__global__ __launch_bounds__(256) void pool_kernel(
    const float* __restrict__ x, const int* __restrict__ batch,
    float* __restrict__ h) {
  int g = blockIdx.x;
  int dchunk = blockIdx.y;
  int t = threadIdx.x;
  int dl = t & 63;
  int nl = t >> 6;
  int d = dchunk * 64 + dl;
  int start = lower_bound_dev(batch, N_NODES, g);
  int end = lower_bound_dev(batch, N_NODES, g + 1);
  float sum = 0.f, mx = 0.f;
  for (int i = start + nl; i < end; i += 4) {
    float v = x[(size_t)i * DIM + d];
    sum += v;
    mx = fmaxf(mx, v);
  }
  __shared__ float ssum[4][64];
  __shared__ float smax[4][64];
  ssum[nl][dl] = sum;
  smax[nl][dl] = mx;
  __syncthreads();
  if (nl == 0) {
    sum = ssum[0][dl] + ssum[1][dl] + ssum[2][dl] + ssum[3][dl];
    mx = fmaxf(fmaxf(smax[0][dl], smax[1][dl]), fmaxf(smax[2][dl], smax[3][dl]));
    float cnt = (float)(end - start);
    h[(size_t)g * (2 * DIM) + d] = sum / fmaxf(cnt, 1.0f);
    h[(size_t)g * (2 * DIM) + DIM + d] = mx;
  }
}

// ---------------- FC head ----------------
__global__ __launch_bounds__(256) void fc_kernel(
    const float* __restrict__ h, const float* __restrict__ fc1_w,
    const float* __restrict__ fc1_b, const float* __restrict__ fc2_w,
    const float* __restrict__ fc2_b, float* __restrict__ out) {
  int g = blockIdx.x;
  int j = threadIdx.x;
  __shared__ float hs[2 * DIM];
  __shared__ float s0[256], s1[256];
  hs[j] = h[(size_t)g * (2 * DIM) + j];
  hs[j + 256] = h[(size_t)g * (2 * DIM) + 256 + j];
  __syncthreads();
  float acc = fc1_b[j];
  for (int k = 0; k < 2 * DIM; ++k) acc += hs[k] * fc1_w[(size_t)k * DIM + j];
  float r = fmaxf(acc, 0.0f);
  s0[j] = r * fc2_w[j * 2 + 0];
  s1[j] = r * fc2_w[j * 2 + 1];
  __syncthreads();
  for (int off = 128; off > 0; off >>= 1) {
    if (j < off) { s0[j] += s0[j + off]; s1[j] += s1[j + off]; }
    __syncthreads();
  }
  if (j == 0) {
    out[g * 2 + 0] = s0[0] + fc2_b[0];
    out[g * 2 + 1] = s1[0] + fc2_b[1];
  }
}

extern "C" void kernel_launch(void* const* d_in, const int* in_sizes, int n_in,
                              void* d_out, int out_size, void* d_ws, size_t ws_size,
                              hipStream_t stream) {
  const float* emb_x = (const float*)d_in[0];
  const int* eidx = (const int*)d_in[1];
  const int* esrc = eidx;
  const int* edst = eidx + N_EDGES;
  const float* ew = (const float*)d_in[2];
  const int* batch = (const int*)d_in[3];
  const float* W1 = (const float*)d_in[4];
  const float* b1 = (const float*)d_in[5];
  const float* W2 = (const float*)d_in[6];
  const float* b2 = (const float*)d_in[7];
  const float* W3 = (const float*)d_in[8];
  const float* b3 = (const float*)d_in[9];
  const float* fc1_w = (const float*)d_in[10];
  const float* fc1_b = (const float*)d_in[11];
  const float* fc2_w = (const float*)d_in[12];
  const float* fc2_b = (const float*)d_in[13];
  float* out = (float*)d_out;

  char* ws = (char*)d_ws;
  size_t off = 0;
  auto take = [&](size_t bytes) -> char* {
    char* p = ws + off;
    off = (off + bytes + 255) & ~(size_t)255;
    return p;
  };
  ushort* XW = (ushort*)take((size_t)NSL * N_PAD * 32 * 2);  // bf16 slice-major gather table
  ushort* Xa = (ushort*)take((size_t)NSL * N_PAD * 32 * 2);  // bf16 slice-major GEMM A
  float* Xf32 = (float*)take((size_t)N_NODES * DIM * 4);     // layer-3 f32 out for pooling
  ushort* WT = (ushort*)take((size_t)6 * 256 * 256 * 2);
  float* dinv = (float*)take(N_NODES * 4);
  int* counts = (int*)take(N_NODES * 4);
  int* rs = (int*)take((N_NODES + 1) * 4);
  int* p_local = (int*)take(N_EDGES * 4);
  int* blockSums = (int*)take(64 * 4);
  int* csrc = (int*)take(N_EDGES * 4);
  float* cw = (float*)take(N_EDGES * 4);
  float* h = (float*)take((size_t)N_GRAPHS * 2 * DIM * 4);

  hipMemsetAsync(counts, 0, N_NODES * 4, stream);

  int eblocks = (N_EDGES + 255) / 256;
  int nblocks = (N_NODES + 255) / 256;

  // CSR build
  count_kernel<<<eblocks, 256, 0, stream>>>(edst, counts, p_local);
  scan_phaseA<<<SCAN_BLOCKS, 256, 0, stream>>>(counts, blockSums);
  scan_phaseB<<<1, 64, 0, stream>>>(blockSums, rs);
  scan_phaseC<<<SCAN_BLOCKS, 256, 0, stream>>>(counts, blockSums, rs);
  fill_kernel<<<eblocks, 256, 0, stream>>>(esrc, edst, ew, rs, p_local, csrc, cw);
  degsum_kernel<<<nblocks, 256, 0, stream>>>(rs, cw, dinv);
  norm_kernel<<<eblocks, 256, 0, stream>>>(csrc, dinv, cw);

  // input prep
  round_x_kernel<<<(N_NODES * DIM / 4 + 255) / 256, 256, 0, stream>>>(
      emb_x, Xa, N_NODES * DIM / 4);
  pad0_kernel<<<(NSL * (N_PAD - N_NODES) * 32 + 255) / 256, 256, 0, stream>>>(Xa);
  prep_w_kernel<<<dim3(256, 3), 256, 0, stream>>>(W1, W2, W3, WT);

  ushort* W1h = WT + 0 * 65536; ushort* W1l = WT + 1 * 65536;
  ushort* W2h = WT + 2 * 65536; ushort* W2l = WT + 3 * 65536;
  ushort* W3h = WT + 4 * 65536; ushort* W3l = WT + 5 * 65536;

  dim3 ggrid(N_PAD / GBM);           // 782 blocks
  int sgrid = (N_NODES / 4) * NSL;   // 100000 blocks

  // layer 1
  gemm_mfma<<<ggrid, 256, 0, stream>>>(Xa, W1h, W1l, XW, N_NODES);
  spmm_slice<0><<<sgrid, 256, 0, stream>>>(XW, rs, csrc, cw, dinv, b1, nullptr, Xa);
  // layer 2
  gemm_mfma<<<ggrid, 256, 0, stream>>>(Xa, W2h, W2l, XW, N_NODES);
  spmm_slice<0><<<sgrid, 256, 0, stream>>>(XW, rs, csrc, cw, dinv, b2, nullptr, Xa);
  // layer 3
  gemm_mfma<<<ggrid, 256, 0, stream>>>(Xa, W3h, W3l, XW, N_NODES);
  spmm_slice<1><<<sgrid, 256, 0, stream>>>(XW, rs, csrc, cw, dinv, b3, Xf32, nullptr);

  pool_kernel<<<dim3(N_GRAPHS, 4), 256, 0, stream>>>(Xf32, batch, h);
  fc_kernel<<<N_GRAPHS, 256, 0, stream>>>(h, fc1_w, fc1_b, fc2_w, fc2_b, out);
}

// Round 7
// 754.888 us; speedup vs baseline: 1.1576x; 1.1576x over previous
//
#include <hip/hip_runtime.h>
#include <math.h>

#define N_NODES 50000
#define N_PAD 50048          // multiple of 64 above 50000
#define N_EDGES 800000
#define DIM 256
#define N_GRAPHS 128
#define NSL 8                // dim slices (one per XCD; 3.2MB slice table fits 4MB L2)

using f32x4 = __attribute__((ext_vector_type(4))) float;
using s16x8 = __attribute__((ext_vector_type(8))) short;

// ---------------- bf16 helpers ----------------
__device__ __forceinline__ ushort bf16_hi(float f) {
  unsigned u = __float_as_uint(f);
  return (ushort)((u + 0x7FFFu + ((u >> 16) & 1u)) >> 16);
}
__device__ __forceinline__ float bf16_up(ushort h) {
  return __uint_as_float(((unsigned)h) << 16);
}
__device__ __forceinline__ void bf16_split(float f, ushort& hh, ushort& ll) {
  hh = bf16_hi(f);
  float d = f - bf16_up(hh);
  ll = bf16_hi(d);
}

// ---------------- CSR build (atomic count only) ----------------
__global__ __launch_bounds__(256) void count_kernel(
    const int* __restrict__ dst, int* __restrict__ counts,
    int* __restrict__ p_local) {
  int e = blockIdx.x * 256 + threadIdx.x;
  if (e < N_EDGES) p_local[e] = atomicAdd(&counts[dst[e]], 1);
}

#define SCAN_CHUNK 1024
#define SCAN_BLOCKS ((N_NODES + SCAN_CHUNK - 1) / SCAN_CHUNK)

__global__ __launch_bounds__(256) void scan_phaseA(
    const int* __restrict__ counts, int* __restrict__ blockSums) {
  __shared__ int sdata[256];
  int b = blockIdx.x, t = threadIdx.x;
  int base = b * SCAN_CHUNK + t * 4;
  int s = 0;
#pragma unroll
  for (int i = 0; i < 4; ++i) {
    int idx = base + i;
    if (idx < N_NODES) s += counts[idx];
  }
  sdata[t] = s;
  __syncthreads();
  for (int off = 128; off > 0; off >>= 1) {
    if (t < off) sdata[t] += sdata[t + off];
    __syncthreads();
  }
  if (t == 0) blockSums[b] = sdata[0];
}

__global__ void scan_phaseB(int* __restrict__ blockSums, int* __restrict__ rs) {
  if (threadIdx.x == 0 && blockIdx.x == 0) {
    int acc = 0;
    for (int i = 0; i < SCAN_BLOCKS; ++i) {
      int v = blockSums[i];
      blockSums[i] = acc;
      acc += v;
    }
    rs[N_NODES] = acc;
  }
}

__global__ __launch_bounds__(256) void scan_phaseC(
    const int* __restrict__ counts, const int* __restrict__ blockSums,
    int* __restrict__ rs) {
  __shared__ int sdata[256];
  int b = blockIdx.x, t = threadIdx.x;
  int base = b * SCAN_CHUNK + t * 4;
  int v[4];
  int s = 0;
#pragma unroll
  for (int i = 0; i < 4; ++i) {
    int idx = base + i;
    v[i] = (idx < N_NODES) ? counts[idx] : 0;
    s += v[i];
  }
  sdata[t] = s;
  __syncthreads();
  for (int off = 1; off < 256; off <<= 1) {
    int x = (t >= off) ? sdata[t - off] : 0;
    __syncthreads();
    sdata[t] += x;
    __syncthreads();
  }
  int excl = (t == 0) ? 0 : sdata[t - 1];
  int o = blockSums[b] + excl;
#pragma unroll
  for (int i = 0; i < 4; ++i) {
    int idx = base + i;
    if (idx < N_NODES) rs[idx] = o;
    o += v[i];
  }
}

// non-atomic fill: pos = rs[dst] + p_local
__global__ __launch_bounds__(256) void fill_kernel(
    const int* __restrict__ src, const int* __restrict__ dst,
    const float* __restrict__ ew, const int* __restrict__ rs,
    const int* __restrict__ p_local,
    int* __restrict__ csrc, float* __restrict__ cw) {
  int e = blockIdx.x * 256 + threadIdx.x;
  if (e < N_EDGES) {
    int d = dst[e];
    int pos = rs[d] + p_local[e];
    csrc[pos] = src[e];
    cw[pos] = ew[e];           // raw ew; normalized later
  }
}

// deg from CSR (coalesced, no atomics) + fused dinv
__global__ __launch_bounds__(256) void degsum_kernel(
    const int* __restrict__ rs, const float* __restrict__ cw,
    float* __restrict__ dinv) {
  int n = blockIdx.x * 256 + threadIdx.x;
  if (n >= N_NODES) return;
  int b = rs[n], e = rs[n + 1];
  float s = 1.0f;              // self-loop weight
  for (int i = b; i < e; ++i) s += cw[i];
  dinv[n] = 1.0f / sqrtf(s);
}

// cw[i] = dinv[src]*ew  (dst factor applied in spmm epilogue)
__global__ __launch_bounds__(256) void norm_kernel(
    const int* __restrict__ csrc, const float* __restrict__ dinv,
    float* __restrict__ cw) {
  int e = blockIdx.x * 256 + threadIdx.x;
  if (e < N_EDGES) cw[e] = cw[e] * dinv[csrc[e]];
}

// ---------------- input prep ----------------
// round emb_x to bf16, slice-major layout [NSL][N_PAD][32]
__global__ __launch_bounds__(256) void round_x_kernel(
    const float* __restrict__ x, ushort* __restrict__ tab, int n4) {
  int i = blockIdx.x * 256 + threadIdx.x;
  if (i >= n4) return;
  int n = i >> 6;              // node (DIM/4 = 64 quads per node)
  int q = i & 63;              // quad within row
  int s = q >> 3;              // slice (8 quads per slice)
  int c = (q & 7) * 4;         // dim within slice
  float4 v = ((const float4*)x)[i];
  ushort4 h;
  h.x = bf16_hi(v.x);
  h.y = bf16_hi(v.y);
  h.z = bf16_hi(v.z);
  h.w = bf16_hi(v.w);
  *(ushort4*)(tab + ((size_t)s * N_PAD + n) * 32 + c) = h;
}

// zero pad rows [N_NODES, N_PAD) of the slice-major A table
__global__ __launch_bounds__(256) void pad0_kernel(ushort* __restrict__ tab) {
  int i = blockIdx.x * 256 + threadIdx.x;           // NSL*(N_PAD-N_NODES)*32
  int c = i & 31;
  int r = (i >> 5) % (N_PAD - N_NODES);
  int s = i / ((N_PAD - N_NODES) * 32);
  if (s < NSL) tab[((size_t)s * N_PAD + N_NODES + r) * 32 + c] = 0;
}

// transpose + split weights: W [K=256][N=256] f32 -> Wt_hi/Wt_lo [N][K] bf16
__global__ __launch_bounds__(256) void prep_w_kernel(
    const float* __restrict__ W1, const float* __restrict__ W2, const float* __restrict__ W3,
    ushort* __restrict__ wt) {
  int k = blockIdx.x;
  int w = blockIdx.y;
  int n = threadIdx.x;
  const float* W = (w == 0) ? W1 : (w == 1) ? W2 : W3;
  float v = W[k * 256 + n];
  ushort h, l;
  bf16_split(v, h, l);
  ushort* hplane = wt + (size_t)w * 2 * 256 * 256;
  ushort* lplane = hplane + 256 * 256;
  hplane[n * 256 + k] = h;
  lplane[n * 256 + k] = l;
}

// ---------------- bf16 MFMA GEMM (A + C slice-major, W hi+lo) ----------
// XW = round_bf16( A @ (Wh+Wl) ); BM=64, BN=256, BK=32, 4 waves, 2-phase dbuf.
#define GBM 64
#define GBK 32

__device__ __forceinline__ void gload16(const void* g, void* l) {
  __builtin_amdgcn_global_load_lds(
      (const __attribute__((address_space(1))) void*)g,
      (__attribute__((address_space(3))) void*)l, 16, 0, 0);
}

__global__ __launch_bounds__(256) void gemm_mfma(
    const ushort* __restrict__ A,                                  // [NSL][N_PAD][32]
    const ushort* __restrict__ Wh, const ushort* __restrict__ Wl,  // [256][256] n-major
    ushort* __restrict__ C, int M) {                               // [NSL][N_PAD][32]
  __shared__ ushort Asl[2][GBM * GBK];   // 2 x 4KB
  __shared__ ushort Bhs[2][256 * GBK];   // 2 x 16KB
  __shared__ ushort Bls[2][256 * GBK];   // 2 x 16KB
  int tid = threadIdx.x;
  int bm = blockIdx.x * GBM;
  int wave = tid >> 6, lane = tid & 63;
  int wc = wave * 64;
  int l15 = lane & 15;
  int lkb = lane >> 4;

  f32x4 acc[4][4];
#pragma unroll
  for (int i = 0; i < 4; ++i)
#pragma unroll
    for (int j = 0; j < 4; ++j) acc[i][j] = (f32x4){0.f, 0.f, 0.f, 0.f};

  int arow = tid & 63, akb = tid >> 6;   // A slot = tid = akb*64+arow

#define STAGE(buf, ts)                                                         \
  do {                                                                         \
    gload16(A + ((size_t)(ts) * N_PAD + bm + arow) * 32 + akb * 8,             \
            &Asl[buf][tid * 8]);                                               \
    _Pragma("unroll") for (int it = 0; it < 4; ++it) {                         \
      gload16(Wh + (size_t)tid * 256 + (ts) * 32 + it * 8,                     \
              &Bhs[buf][(it * 256 + tid) * 8]);                                \
      gload16(Wl + (size_t)tid * 256 + (ts) * 32 + it * 8,                     \
              &Bls[buf][(it * 256 + tid) * 8]);                                \
    }                                                                          \
  } while (0)

  STAGE(0, 0);
  __syncthreads();
  int cur = 0;
  for (int t = 0; t < 8; ++t) {
    if (t < 7) STAGE(cur ^ 1, t + 1);   // prefetch next k-step (= next slice)
    s16x8 af[4], bh[4], bl[4];
#pragma unroll
    for (int f = 0; f < 4; ++f) {
      af[f] = *(const s16x8*)(&Asl[cur][(lkb * 64 + f * 16 + l15) * 8]);
      bh[f] = *(const s16x8*)(&Bhs[cur][(lkb * 256 + wc + f * 16 + l15) * 8]);
      bl[f] = *(const s16x8*)(&Bls[cur][(lkb * 256 + wc + f * 16 + l15) * 8]);
    }
#pragma unroll
    for (int i = 0; i < 4; ++i)
#pragma unroll
      for (int j = 0; j < 4; ++j) {
        acc[i][j] = __builtin_amdgcn_mfma_f32_16x16x32_bf16(af[i], bh[j], acc[i][j], 0, 0, 0);
        acc[i][j] = __builtin_amdgcn_mfma_f32_16x16x32_bf16(af[i], bl[j], acc[i][j], 0, 0, 0);
      }
    __syncthreads();
    cur ^= 1;
  }
#undef STAGE

#pragma unroll
  for (int i = 0; i < 4; ++i) {
    int rbase = bm + i * 16 + (lane >> 4) * 4;
#pragma unroll
    for (int j = 0; j < 4; ++j) {
      int col = wc + j * 16 + l15;
      size_t cbase = (size_t)(col >> 5) * N_PAD * 32 + (col & 31);
#pragma unroll
      for (int r = 0; r < 4; ++r) {
        int row = rbase + r;
        if (row < M) C[cbase + (size_t)row * 32] = bf16_hi(acc[i][j][r]);
      }
    }
  }
}

// ---------------- XCD-sliced SpMM v2: 16 edges/iter, 16B lane loads ----------
// block = 4 waves = 4 nodes of one slice; slice = blockIdx&7 (round-robin->XCD).
// lane = (eg 0..15, q 0..3): eg = edge slot, q = 16B chunk of the 64B slice row.
// Per iter a wave gathers 16 full edge-rows (4 x ushort8 each).
// Epilogue: xor-shuffle reduce over eg; eg==0 lanes write.
// result = di * sum(cw_norm * x_src) + di^2 * x_self + bias, relu.
// MODE 0: write bf16 slice-major table; MODE 1: write f32 row-major.
template <int MODE>
__global__ __launch_bounds__(256) void spmm_slice2(
    const ushort* __restrict__ tab, const int* __restrict__ rs,
    const int* __restrict__ csrc, const float* __restrict__ cw,
    const float* __restrict__ dinv, const float* __restrict__ bias,
    float* __restrict__ xf32, ushort* __restrict__ xout) {
  int bid = blockIdx.x;
  int s = bid & 7;
  int g = bid >> 3;
  int wave = threadIdx.x >> 6, lane = threadIdx.x & 63;
  int n = g * 4 + wave;              // 50000 = 12500*4
  int eg = lane >> 2;                // edge slot 0..15
  int q = lane & 3;                  // 16B chunk 0..3
  const ushort* base = tab + (size_t)s * N_PAD * 32 + q * 8;
  float acc[8] = {};
  int beg = rs[n], end = rs[n + 1];
  for (int i = beg + eg; i < end; i += 16) {
    int idx = csrc[i];
    float w = cw[i];
    s16x8 v = *(const s16x8*)(base + (size_t)idx * 32);
#pragma unroll
    for (int j = 0; j < 8; ++j) acc[j] += w * bf16_up((ushort)v[j]);
  }
  // reduce over the 16 edge slots (lane bits 2..5)
#pragma unroll
  for (int k = 4; k <= 32; k <<= 1) {
#pragma unroll
    for (int j = 0; j < 8; ++j) acc[j] += __shfl_xor(acc[j], k);
  }
  if (eg == 0) {
    float di = dinv[n];
    float dd = di * di;
    s16x8 sv = *(const s16x8*)(base + (size_t)n * 32);
    int d0 = s * 32 + q * 8;
    const float4* bb = (const float4*)(bias + d0);
    float4 b0 = bb[0], b1 = bb[1];
    float r[8];
#pragma unroll
    for (int j = 0; j < 8; ++j) r[j] = di * acc[j] + dd * bf16_up((ushort)sv[j]);
    r[0] = fmaxf(r[0] + b0.x, 0.f);
    r[1] = fmaxf(r[1] + b0.y, 0.f);
    r[2] = fmaxf(r[2] + b0.z, 0.f);
    r[3] = fmaxf(r[3] + b0.w, 0.f);
    r[4] = fmaxf(r[4] + b1.x, 0.f);
    r[5] = fmaxf(r[5] + b1.y, 0.f);
    r[6] = fmaxf(r[6] + b1.z, 0.f);
    r[7] = fmaxf(r[7] + b1.w, 0.f);
    if (MODE == 1) {
      float4 a0, a1;
      a0.x = r[0]; a0.y = r[1]; a0.z = r[2]; a0.w = r[3];
      a1.x = r[4]; a1.y = r[5]; a1.z = r[6]; a1.w = r[7];
      float* p = xf32 + (size_t)n * 256 + d0;
      *(float4*)p = a0;
      *(float4*)(p + 4) = a1;
    } else {
      s16x8 hv;
#pragma unroll
      for (int j = 0; j < 8; ++j) hv[j] = (short)bf16_hi(r[j]);
      *(s16x8*)(xout + ((size_t)s * N_PAD + n) * 32 + q * 8) = hv;
    }
  }
}

// ---------------- pooling ----------------
__device__ __forceinline__ int lower_bound_dev(const int* a, int n, int key) {
  int lo = 0, hi = n;
  while (lo < hi) {
    int mid = (lo + hi) >> 1;
    if (a[mid] < key) lo = mid + 1; else hi = mid;
  }
  return lo;
}

__global__ __launch_bounds__(256) void pool_kernel(
    const float* __restrict__ x, const int* __restrict__ batch,
    float* __restrict__ h) {
  int g = blockIdx.x;
  int dchunk = blockIdx.y;
  int t = threadIdx.x;
  int dl = t & 63;
  int nl = t >> 6;
  int d = dchunk * 64 + dl;
  int start = lower_bound_dev(batch, N_NODES, g);
  int end = lower_bound_dev(batch, N_NODES, g + 1);
  float sum = 0.f, mx = 0.f;
  for (int i = start + nl; i < end; i += 4) {
    float v = x[(size_t)i * DIM + d];
    sum += v;
    mx = fmaxf(mx, v);
  }
  __shared__ float ssum[4][64];
  __shared__ float smax[4][64];
  ssum[nl][dl] = sum;
  smax[nl][dl] = mx;
  __syncthreads();
  if (nl == 0) {
    sum = ssum[0][dl] + ssum[1][dl] + ssum[2][dl] + ssum[3][dl];
    mx = fmaxf(fmaxf(smax[0][dl], smax[1][dl]), fmaxf(smax[2][dl], smax[3][dl]));
    float cnt = (float)(end - start);
    h[(size_t)g * (2 * DIM) + d] = sum / fmaxf(cnt, 1.0f);
    h[(size_t)g * (2 * DIM) + DIM + d] = mx;
  }
}

// ---------------- FC head ----------------
__global__ __launch_bounds__(256) void fc_kernel(
    const float* __restrict__ h, const float* __restrict__ fc1_w,
    const float* __restrict__ fc1_b, const float* __restrict__ fc2_w,
    const float* __restrict__ fc2_b, float* __restrict__ out) {
  int g = blockIdx.x;
  int j = threadIdx.x;
  __shared__ float hs[2 * DIM];
  __shared__ float s0[256], s1[256];
  hs[j] = h[(size_t)g * (2 * DIM) + j];
  hs[j + 256] = h[(size_t)g * (2 * DIM) + 256 + j];
  __syncthreads();
  float acc = fc1_b[j];
  for (int k = 0; k < 2 * DIM; ++k) acc += hs[k] * fc1_w[(size_t)k * DIM + j];
  float r = fmaxf(acc, 0.0f);
  s0[j] = r * fc2_w[j * 2 + 0];
  s1[j] = r * fc2_w[j * 2 + 1];
  __syncthreads();
  for (int off = 128; off > 0; off >>= 1) {
    if (j < off) { s0[j] += s0[j + off]; s1[j] += s1[j + off]; }
    __syncthreads();
  }
  if (j == 0) {
    out[g * 2 + 0] = s0[0] + fc2_b[0];
    out[g * 2 + 1] = s1[0] + fc2_b[1];
  }
}

extern "C" void kernel_launch(void* const* d_in, const int* in_sizes, int n_in,
                              void* d_out, int out_size, void* d_ws, size_t ws_size,
                              hipStream_t stream) {
  const float* emb_x = (const float*)d_in[0];
  const int* eidx = (const int*)d_in[1];
  const int* esrc = eidx;
  const int* edst = eidx + N_EDGES;
  const float* ew = (const float*)d_in[2];
  const int* batch = (const int*)d_in[3];
  const float* W1 = (const float*)d_in[4];
  const float* b1 = (const float*)d_in[5];
  const float* W2 = (const float*)d_in[6];
  const float* b2 = (const float*)d_in[7];
  const float* W3 = (const float*)d_in[8];
  const float* b3 = (const float*)d_in[9];
  const float* fc1_w = (const float*)d_in[10];
  const float* fc1_b = (const float*)d_in[11];
  const float* fc2_w = (const float*)d_in[12];
  const float* fc2_b = (const float*)d_in[13];
  float* out = (float*)d_out;

  char* ws = (char*)d_ws;
  size_t off = 0;
  auto take = [&](size_t bytes) -> char* {
    char* p = ws + off;
    off = (off + bytes + 255) & ~(size_t)255;
    return p;
  };
  ushort* XW = (ushort*)take((size_t)NSL * N_PAD * 32 * 2);  // bf16 slice-major gather table
  ushort* Xa = (ushort*)take((size_t)NSL * N_PAD * 32 * 2);  // bf16 slice-major GEMM A
  float* Xf32 = (float*)take((size_t)N_NODES * DIM * 4);     // layer-3 f32 out for pooling
  ushort* WT = (ushort*)take((size_t)6 * 256 * 256 * 2);
  float* dinv = (float*)take(N_NODES * 4);
  int* counts = (int*)take(N_NODES * 4);
  int* rs = (int*)take((N_NODES + 1) * 4);
  int* p_local = (int*)take(N_EDGES * 4);
  int* blockSums = (int*)take(64 * 4);
  int* csrc = (int*)take(N_EDGES * 4);
  float* cw = (float*)take(N_EDGES * 4);
  float* h = (float*)take((size_t)N_GRAPHS * 2 * DIM * 4);

  hipMemsetAsync(counts, 0, N_NODES * 4, stream);

  int eblocks = (N_EDGES + 255) / 256;
  int nblocks = (N_NODES + 255) / 256;

  // CSR build
  count_kernel<<<eblocks, 256, 0, stream>>>(edst, counts, p_local);
  scan_phaseA<<<SCAN_BLOCKS, 256, 0, stream>>>(counts, blockSums);
  scan_phaseB<<<1, 64, 0, stream>>>(blockSums, rs);
  scan_phaseC<<<SCAN_BLOCKS, 256, 0, stream>>>(counts, blockSums, rs);
  fill_kernel<<<eblocks, 256, 0, stream>>>(esrc, edst, ew, rs, p_local, csrc, cw);
  degsum_kernel<<<nblocks, 256, 0, stream>>>(rs, cw, dinv);
  norm_kernel<<<eblocks, 256, 0, stream>>>(csrc, dinv, cw);

  // input prep
  round_x_kernel<<<(N_NODES * DIM / 4 + 255) / 256, 256, 0, stream>>>(
      emb_x, Xa, N_NODES * DIM / 4);
  pad0_kernel<<<(NSL * (N_PAD - N_NODES) * 32 + 255) / 256, 256, 0, stream>>>(Xa);
  prep_w_kernel<<<dim3(256, 3), 256, 0, stream>>>(W1, W2, W3, WT);

  ushort* W1h = WT + 0 * 65536; ushort* W1l = WT + 1 * 65536;
  ushort* W2h = WT + 2 * 65536; ushort* W2l = WT + 3 * 65536;
  ushort* W3h = WT + 4 * 65536; ushort* W3l = WT + 5 * 65536;

  dim3 ggrid(N_PAD / GBM);           // 782 blocks
  int sgrid = (N_NODES / 4) * NSL;   // 100000 blocks

  // layer 1
  gemm_mfma<<<ggrid, 256, 0, stream>>>(Xa, W1h, W1l, XW, N_NODES);
  spmm_slice2<0><<<sgrid, 256, 0, stream>>>(XW, rs, csrc, cw, dinv, b1, nullptr, Xa);
  // layer 2
  gemm_mfma<<<ggrid, 256, 0, stream>>>(Xa, W2h, W2l, XW, N_NODES);
  spmm_slice2<0><<<sgrid, 256, 0, stream>>>(XW, rs, csrc, cw, dinv, b2, nullptr, Xa);
  // layer 3
  gemm_mfma<<<ggrid, 256, 0, stream>>>(Xa, W3h, W3l, XW, N_NODES);
  spmm_slice2<1><<<sgrid, 256, 0, stream>>>(XW, rs, csrc, cw, dinv, b3, Xf32, nullptr);

  pool_kernel<<<dim3(N_GRAPHS, 4), 256, 0, stream>>>(Xf32, batch, h);
  fc_kernel<<<N_GRAPHS, 256, 0, stream>>>(h, fc1_w, fc1_b, fc2_w, fc2_b, out);
}

// Round 8
// 460.882 us; speedup vs baseline: 1.8961x; 1.6379x over previous
//
#include <hip/hip_runtime.h>
#include <math.h>

#define N_NODES 50000
#define N_PAD 50048          // multiple of 64 above 50000
#define N_EDGES 800000
#define DIM 256
#define N_GRAPHS 128

using f32x4 = __attribute__((ext_vector_type(4))) float;
using s16x8 = __attribute__((ext_vector_type(8))) short;

// ---------------- bf16 helpers ----------------
__device__ __forceinline__ ushort bf16_hi(float f) {
  unsigned u = __float_as_uint(f);
  return (ushort)((u + 0x7FFFu + ((u >> 16) & 1u)) >> 16);
}
__device__ __forceinline__ float bf16_up(ushort h) {
  return __uint_as_float(((unsigned)h) << 16);
}
__device__ __forceinline__ void bf16_split(float f, ushort& hh, ushort& ll) {
  hh = bf16_hi(f);
  float d = f - bf16_up(hh);
  ll = bf16_hi(d);
}
__device__ __forceinline__ float up_lo(unsigned u) {  // low bf16 of packed u32
  return __uint_as_float(u << 16);
}
__device__ __forceinline__ float up_hi(unsigned u) {  // high bf16 of packed u32
  return __uint_as_float(u & 0xffff0000u);
}

// ---------------- CSR build (atomic count only) ----------------
__global__ __launch_bounds__(256) void count_kernel(
    const int* __restrict__ dst, int* __restrict__ counts,
    int* __restrict__ p_local) {
  int e = blockIdx.x * 256 + threadIdx.x;
  if (e < N_EDGES) p_local[e] = atomicAdd(&counts[dst[e]], 1);
}

#define SCAN_CHUNK 1024
#define SCAN_BLOCKS ((N_NODES + SCAN_CHUNK - 1) / SCAN_CHUNK)

__global__ __launch_bounds__(256) void scan_phaseA(
    const int* __restrict__ counts, int* __restrict__ blockSums) {
  __shared__ int sdata[256];
  int b = blockIdx.x, t = threadIdx.x;
  int base = b * SCAN_CHUNK + t * 4;
  int s = 0;
#pragma unroll
  for (int i = 0; i < 4; ++i) {
    int idx = base + i;
    if (idx < N_NODES) s += counts[idx];
  }
  sdata[t] = s;
  __syncthreads();
  for (int off = 128; off > 0; off >>= 1) {
    if (t < off) sdata[t] += sdata[t + off];
    __syncthreads();
  }
  if (t == 0) blockSums[b] = sdata[0];
}

__global__ void scan_phaseB(int* __restrict__ blockSums, int* __restrict__ rs) {
  if (threadIdx.x == 0 && blockIdx.x == 0) {
    int acc = 0;
    for (int i = 0; i < SCAN_BLOCKS; ++i) {
      int v = blockSums[i];
      blockSums[i] = acc;
      acc += v;
    }
    rs[N_NODES] = acc;
  }
}

__global__ __launch_bounds__(256) void scan_phaseC(
    const int* __restrict__ counts, const int* __restrict__ blockSums,
    int* __restrict__ rs) {
  __shared__ int sdata[256];
  int b = blockIdx.x, t = threadIdx.x;
  int base = b * SCAN_CHUNK + t * 4;
  int v[4];
  int s = 0;
#pragma unroll
  for (int i = 0; i < 4; ++i) {
    int idx = base + i;
    v[i] = (idx < N_NODES) ? counts[idx] : 0;
    s += v[i];
  }
  sdata[t] = s;
  __syncthreads();
  for (int off = 1; off < 256; off <<= 1) {
    int x = (t >= off) ? sdata[t - off] : 0;
    __syncthreads();
    sdata[t] += x;
    __syncthreads();
  }
  int excl = (t == 0) ? 0 : sdata[t - 1];
  int o = blockSums[b] + excl;
#pragma unroll
  for (int i = 0; i < 4; ++i) {
    int idx = base + i;
    if (idx < N_NODES) rs[idx] = o;
    o += v[i];
  }
}

// non-atomic fill: pos = rs[dst] + p_local
__global__ __launch_bounds__(256) void fill_kernel(
    const int* __restrict__ src, const int* __restrict__ dst,
    const float* __restrict__ ew, const int* __restrict__ rs,
    const int* __restrict__ p_local,
    int* __restrict__ csrc, float* __restrict__ cw) {
  int e = blockIdx.x * 256 + threadIdx.x;
  if (e < N_EDGES) {
    int d = dst[e];
    int pos = rs[d] + p_local[e];
    csrc[pos] = src[e];
    cw[pos] = ew[e];           // raw ew; normalized later
  }
}

// deg from CSR (coalesced, no atomics) + fused dinv
__global__ __launch_bounds__(256) void degsum_kernel(
    const int* __restrict__ rs, const float* __restrict__ cw,
    float* __restrict__ dinv) {
  int n = blockIdx.x * 256 + threadIdx.x;
  if (n >= N_NODES) return;
  int b = rs[n], e = rs[n + 1];
  float s = 1.0f;              // self-loop weight
  for (int i = b; i < e; ++i) s += cw[i];
  dinv[n] = 1.0f / sqrtf(s);
}

// cw[i] = dinv[src]*ew  (dst factor applied in spmm epilogue)
__global__ __launch_bounds__(256) void norm_kernel(
    const int* __restrict__ csrc, const float* __restrict__ dinv,
    float* __restrict__ cw) {
  int e = blockIdx.x * 256 + threadIdx.x;
  if (e < N_EDGES) cw[e] = cw[e] * dinv[csrc[e]];
}

// ---------------- input prep ----------------
// round emb_x to bf16, row-major [N_PAD][256]
__global__ __launch_bounds__(256) void round_x_kernel(
    const float* __restrict__ x, ushort* __restrict__ tab, int n4) {
  int i = blockIdx.x * 256 + threadIdx.x;
  if (i >= n4) return;
  float4 v = ((const float4*)x)[i];
  ushort4 h;
  h.x = bf16_hi(v.x);
  h.y = bf16_hi(v.y);
  h.z = bf16_hi(v.z);
  h.w = bf16_hi(v.w);
  ((ushort4*)tab)[i] = h;
}

// transpose + split weights: W [K=256][N=256] f32 -> Wt_hi/Wt_lo [N][K] bf16
__global__ __launch_bounds__(256) void prep_w_kernel(
    const float* __restrict__ W1, const float* __restrict__ W2, const float* __restrict__ W3,
    ushort* __restrict__ wt) {
  int k = blockIdx.x;
  int w = blockIdx.y;
  int n = threadIdx.x;
  const float* W = (w == 0) ? W1 : (w == 1) ? W2 : W3;
  float v = W[k * 256 + n];
  ushort h, l;
  bf16_split(v, h, l);
  ushort* hplane = wt + (size_t)w * 2 * 256 * 256;
  ushort* lplane = hplane + 256 * 256;
  hplane[n * 256 + k] = h;
  lplane[n * 256 + k] = l;
}

// ---------------- bf16 MFMA GEMM: A in LDS (8KB dbuf), W direct from L2 ----
// XW = round_bf16( A @ (Wh+Wl) ); BM=64, BN=256, BK=32, 4 waves.
// B (W hi/lo) is 256KB, L2-hot, shared by all blocks -> no LDS staging; each
// wave loads its 4+4 16B fragments per k-step straight from global.
#define GBM 64
#define GBK 32

__device__ __forceinline__ void gload16(const void* g, void* l) {
  __builtin_amdgcn_global_load_lds(
      (const __attribute__((address_space(1))) void*)g,
      (__attribute__((address_space(3))) void*)l, 16, 0, 0);
}

__global__ __launch_bounds__(256) void gemm_mfma(
    const ushort* __restrict__ A,                                  // [N_PAD][256] bf16
    const ushort* __restrict__ Wh, const ushort* __restrict__ Wl,  // [256][256] n-major
    ushort* __restrict__ C, int M) {                               // [N_PAD][256] bf16
  __shared__ ushort Asl[2][GBM * GBK];   // 2 x 4KB
  int tid = threadIdx.x;
  int bm = blockIdx.x * GBM;
  int wave = tid >> 6, lane = tid & 63;
  int wc = wave * 64;
  int l15 = lane & 15;
  int lkb = lane >> 4;

  f32x4 acc[4][4];
#pragma unroll
  for (int i = 0; i < 4; ++i)
#pragma unroll
    for (int j = 0; j < 4; ++j) acc[i][j] = (f32x4){0.f, 0.f, 0.f, 0.f};

  int arow = tid & 63, akb = tid >> 6;   // A slot = tid = akb*64 + arow

#define STAGE_A(buf, ts)                                                       \
  gload16(A + (size_t)(bm + arow) * 256 + (ts) * 32 + akb * 8,                 \
          &Asl[buf][tid * 8])

  STAGE_A(0, 0);
  __syncthreads();
  int cur = 0;
  for (int t = 0; t < 8; ++t) {
    if (t < 7) STAGE_A(cur ^ 1, t + 1);   // prefetch next A k-step
    s16x8 af[4], bh[4], bl[4];
#pragma unroll
    for (int f = 0; f < 4; ++f) {
      size_t woff = (size_t)(wc + f * 16 + l15) * 256 + t * 32 + lkb * 8;
      bh[f] = *(const s16x8*)(Wh + woff);
      bl[f] = *(const s16x8*)(Wl + woff);
    }
#pragma unroll
    for (int f = 0; f < 4; ++f)
      af[f] = *(const s16x8*)(&Asl[cur][(lkb * 64 + f * 16 + l15) * 8]);
#pragma unroll
    for (int i = 0; i < 4; ++i)
#pragma unroll
      for (int j = 0; j < 4; ++j) {
        acc[i][j] = __builtin_amdgcn_mfma_f32_16x16x32_bf16(af[i], bh[j], acc[i][j], 0, 0, 0);
        acc[i][j] = __builtin_amdgcn_mfma_f32_16x16x32_bf16(af[i], bl[j], acc[i][j], 0, 0, 0);
      }
    __syncthreads();
    cur ^= 1;
  }
#undef STAGE_A

#pragma unroll
  for (int i = 0; i < 4; ++i) {
    int rbase = bm + i * 16 + (lane >> 4) * 4;
#pragma unroll
    for (int j = 0; j < 4; ++j) {
      int col = wc + j * 16 + l15;
#pragma unroll
      for (int r = 0; r < 4; ++r) {
        int row = rbase + r;
        if (row < M) C[(size_t)row * 256 + col] = bf16_hi(acc[i][j][r]);
      }
    }
  }
}

// ---------------- SpMM: wave = node, lane = 8B (4 bf16 dims), 8-deep unroll --
// Edge metadata (rs/csrc/cw) made wave-uniform via readfirstlane -> s_loads.
// result = di * sum(cw_norm * x_src) + di^2 * x_self + bias, relu.
// MODE 0: write bf16 row-major table; MODE 1: write f32 row-major.
template <int MODE>
__global__ __launch_bounds__(256) void spmm_row(
    const ushort* __restrict__ xw, const int* __restrict__ rs,
    const int* __restrict__ csrc, const float* __restrict__ cw,
    const float* __restrict__ dinv, const float* __restrict__ bias,
    float* __restrict__ xf32, ushort* __restrict__ xout) {
  int wave = threadIdx.x >> 6, lane = threadIdx.x & 63;
  int n = __builtin_amdgcn_readfirstlane(blockIdx.x * 4 + wave);  // 50000=12500*4
  const uint2* base = (const uint2*)xw;   // 8B units; 64 per row
  size_t rowoff = (size_t)n * 64 + lane;
  float a0 = 0.f, a1 = 0.f, a2 = 0.f, a3 = 0.f;
  int beg = __builtin_amdgcn_readfirstlane(rs[n]);
  int end = __builtin_amdgcn_readfirstlane(rs[n + 1]);
  int i = beg;
  for (; i + 8 <= end; i += 8) {
    int idx[8];
    float w[8];
    uint2 v[8];
#pragma unroll
    for (int u = 0; u < 8; ++u) { idx[u] = csrc[i + u]; w[u] = cw[i + u]; }
#pragma unroll
    for (int u = 0; u < 8; ++u) v[u] = base[(size_t)idx[u] * 64 + lane];
#pragma unroll
    for (int u = 0; u < 8; ++u) {
      a0 += w[u] * up_lo(v[u].x);
      a1 += w[u] * up_hi(v[u].x);
      a2 += w[u] * up_lo(v[u].y);
      a3 += w[u] * up_hi(v[u].y);
    }
  }
  for (; i < end; ++i) {
    float w0 = cw[i];
    uint2 v0 = base[(size_t)csrc[i] * 64 + lane];
    a0 += w0 * up_lo(v0.x);
    a1 += w0 * up_hi(v0.x);
    a2 += w0 * up_lo(v0.y);
    a3 += w0 * up_hi(v0.y);
  }
  float di = dinv[n];
  float dd = di * di;
  uint2 sv = base[rowoff];
  float4 b = ((const float4*)bias)[lane];
  float r0 = fmaxf(di * a0 + dd * up_lo(sv.x) + b.x, 0.f);
  float r1 = fmaxf(di * a1 + dd * up_hi(sv.x) + b.y, 0.f);
  float r2 = fmaxf(di * a2 + dd * up_lo(sv.y) + b.z, 0.f);
  float r3 = fmaxf(di * a3 + dd * up_hi(sv.y) + b.w, 0.f);
  if (MODE == 1) {
    float4 r;
    r.x = r0; r.y = r1; r.z = r2; r.w = r3;
    ((float4*)xf32)[rowoff] = r;
  } else {
    uint2 hv;
    hv.x = (unsigned)bf16_hi(r0) | ((unsigned)bf16_hi(r1) << 16);
    hv.y = (unsigned)bf16_hi(r2) | ((unsigned)bf16_hi(r3) << 16);
    ((uint2*)xout)[rowoff] = hv;
  }
}

// ---------------- pooling ----------------
__device__ __forceinline__ int lower_bound_dev(const int* a, int n, int key) {
  int lo = 0, hi = n;
  while (lo < hi) {
    int mid = (lo + hi) >> 1;
    if (a[mid] < key) lo = mid + 1; else hi = mid;
  }
  return lo;
}

__global__ __launch_bounds__(256) void pool_kernel(
    const float* __restrict__ x, const int* __restrict__ batch,
    float* __restrict__ h) {
  int g = blockIdx.x;
  int dchunk = blockIdx.y;
  int t = threadIdx.x;
  int dl = t & 63;
  int nl = t >> 6;
  int d = dchunk * 64 + dl;
  int start = lower_bound_dev(batch, N_NODES, g);
  int end = lower_bound_dev(batch, N_NODES, g + 1);
  float sum = 0.f, mx = 0.f;
  for (int i = start + nl; i < end; i += 4) {
    float v = x[(size_t)i * DIM + d];
    sum += v;
    mx = fmaxf(mx, v);
  }
  __shared__ float ssum[4][64];
  __shared__ float smax[4][64];
  ssum[nl][dl] = sum;
  smax[nl][dl] = mx;
  __syncthreads();
  if (nl == 0) {
    sum = ssum[0][dl] + ssum[1][dl] + ssum[2][dl] + ssum[3][dl];
    mx = fmaxf(fmaxf(smax[0][dl], smax[1][dl]), fmaxf(smax[2][dl], smax[3][dl]));
    float cnt = (float)(end - start);
    h[(size_t)g * (2 * DIM) + d] = sum / fmaxf(cnt, 1.0f);
    h[(size_t)g * (2 * DIM) + DIM + d] = mx;
  }
}

// ---------------- FC head ----------------
__global__ __launch_bounds__(256) void fc_kernel(
    const float* __restrict__ h, const float* __restrict__ fc1_w,
    const float* __restrict__ fc1_b, const float* __restrict__ fc2_w,
    const float* __restrict__ fc2_b, float* __restrict__ out) {
  int g = blockIdx.x;
  int j = threadIdx.x;
  __shared__ float hs[2 * DIM];
  __shared__ float s0[256], s1[256];
  hs[j] = h[(size_t)g * (2 * DIM) + j];
  hs[j + 256] = h[(size_t)g * (2 * DIM) + 256 + j];
  __syncthreads();
  float acc = fc1_b[j];
  for (int k = 0; k < 2 * DIM; ++k) acc += hs[k] * fc1_w[(size_t)k * DIM + j];
  float r = fmaxf(acc, 0.0f);
  s0[j] = r * fc2_w[j * 2 + 0];
  s1[j] = r * fc2_w[j * 2 + 1];
  __syncthreads();
  for (int off = 128; off > 0; off >>= 1) {
    if (j < off) { s0[j] += s0[j + off]; s1[j] += s1[j + off]; }
    __syncthreads();
  }
  if (j == 0) {
    out[g * 2 + 0] = s0[0] + fc2_b[0];
    out[g * 2 + 1] = s1[0] + fc2_b[1];
  }
}

extern "C" void kernel_launch(void* const* d_in, const int* in_sizes, int n_in,
                              void* d_out, int out_size, void* d_ws, size_t ws_size,
                              hipStream_t stream) {
  const float* emb_x = (const float*)d_in[0];
  const int* eidx = (const int*)d_in[1];
  const int* esrc = eidx;
  const int* edst = eidx + N_EDGES;
  const float* ew = (const float*)d_in[2];
  const int* batch = (const int*)d_in[3];
  const float* W1 = (const float*)d_in[4];
  const float* b1 = (const float*)d_in[5];
  const float* W2 = (const float*)d_in[6];
  const float* b2 = (const float*)d_in[7];
  const float* W3 = (const float*)d_in[8];
  const float* b3 = (const float*)d_in[9];
  const float* fc1_w = (const float*)d_in[10];
  const float* fc1_b = (const float*)d_in[11];
  const float* fc2_w = (const float*)d_in[12];
  const float* fc2_b = (const float*)d_in[13];
  float* out = (float*)d_out;

  char* ws = (char*)d_ws;
  size_t off = 0;
  auto take = [&](size_t bytes) -> char* {
    char* p = ws + off;
    off = (off + bytes + 255) & ~(size_t)255;
    return p;
  };
  ushort* XW = (ushort*)take((size_t)N_PAD * DIM * 2);    // bf16 gather table
  ushort* Xa = (ushort*)take((size_t)N_PAD * DIM * 2);    // bf16 GEMM A
  float* Xf32 = (float*)take((size_t)N_NODES * DIM * 4);  // layer-3 f32 out for pooling
  ushort* WT = (ushort*)take((size_t)6 * 256 * 256 * 2);
  float* dinv = (float*)take(N_NODES * 4);
  int* counts = (int*)take(N_NODES * 4);
  int* rs = (int*)take((N_NODES + 1) * 4);
  int* p_local = (int*)take(N_EDGES * 4);
  int* blockSums = (int*)take(64 * 4);
  int* csrc = (int*)take(N_EDGES * 4);
  float* cw = (float*)take(N_EDGES * 4);
  float* h = (float*)take((size_t)N_GRAPHS * 2 * DIM * 4);

  hipMemsetAsync(counts, 0, N_NODES * 4, stream);
  // zero padded tail rows of Xa (read by gemm as A rows >= N_NODES)
  hipMemsetAsync(Xa + (size_t)N_NODES * DIM, 0, (size_t)(N_PAD - N_NODES) * DIM * 2, stream);

  int eblocks = (N_EDGES + 255) / 256;
  int nblocks = (N_NODES + 255) / 256;

  // CSR build
  count_kernel<<<eblocks, 256, 0, stream>>>(edst, counts, p_local);
  scan_phaseA<<<SCAN_BLOCKS, 256, 0, stream>>>(counts, blockSums);
  scan_phaseB<<<1, 64, 0, stream>>>(blockSums, rs);
  scan_phaseC<<<SCAN_BLOCKS, 256, 0, stream>>>(counts, blockSums, rs);
  fill_kernel<<<eblocks, 256, 0, stream>>>(esrc, edst, ew, rs, p_local, csrc, cw);
  degsum_kernel<<<nblocks, 256, 0, stream>>>(rs, cw, dinv);
  norm_kernel<<<eblocks, 256, 0, stream>>>(csrc, dinv, cw);

  // input prep
  round_x_kernel<<<(N_NODES * DIM / 4 + 255) / 256, 256, 0, stream>>>(
      emb_x, Xa, N_NODES * DIM / 4);
  prep_w_kernel<<<dim3(256, 3), 256, 0, stream>>>(W1, W2, W3, WT);

  ushort* W1h = WT + 0 * 65536; ushort* W1l = WT + 1 * 65536;
  ushort* W2h = WT + 2 * 65536; ushort* W2l = WT + 3 * 65536;
  ushort* W3h = WT + 4 * 65536; ushort* W3l = WT + 5 * 65536;

  dim3 ggrid(N_PAD / GBM);           // 782 blocks
  int sgrid = N_NODES / 4;           // 12500 blocks

  // layer 1
  gemm_mfma<<<ggrid, 256, 0, stream>>>(Xa, W1h, W1l, XW, N_NODES);
  spmm_row<0><<<sgrid, 256, 0, stream>>>(XW, rs, csrc, cw, dinv, b1, nullptr, Xa);
  // layer 2
  gemm_mfma<<<ggrid, 256, 0, stream>>>(Xa, W2h, W2l, XW, N_NODES);
  spmm_row<0><<<sgrid, 256, 0, stream>>>(XW, rs, csrc, cw, dinv, b2, nullptr, Xa);
  // layer 3
  gemm_mfma<<<ggrid, 256, 0, stream>>>(Xa, W3h, W3l, XW, N_NODES);
  spmm_row<1><<<sgrid, 256, 0, stream>>>(XW, rs, csrc, cw, dinv, b3, Xf32, nullptr);

  pool_kernel<<<dim3(N_GRAPHS, 4), 256, 0, stream>>>(Xf32, batch, h);
  fc_kernel<<<N_GRAPHS, 256, 0, stream>>>(h, fc1_w, fc1_b, fc2_w, fc2_b, out);
}